// Round 7
// baseline (2951.769 us; speedup 1.0000x reference)
//
#include <hip/hip_runtime.h>
#include <hip/hip_fp16.h>
#include <math.h>

#define BATCH 128
#define NDIM 512
#define NPAIR 256          // row-pairs per batch
#define POWER_ITERS 30
#define N_ITERS 500
// 1024 threads = 8 groups x 128 threads; group owns 32 pairs; thread: 32 pairs x 4 cols.
#define REGK 16            // pairs in registers (64 VGPR)
#define LDSP 8             // pairs in LDS (8 groups x 8 x 2KB = 128 KB)
#define STRM 8             // pairs streamed from L2 (two 4-deep batches)

typedef _Float16 half2_t __attribute__((ext_vector_type(2)));

union H2x4 { float4 f4; half2_t h[4]; };

// ---------------- helpers ----------------
__device__ __forceinline__ float4 ld4(const float* p) { return *(const float4*)p; }
__device__ __forceinline__ float4 f4_add(float4 a, float4 b) {
  return make_float4(a.x + b.x, a.y + b.y, a.z + b.z, a.w + b.w);
}
__device__ __forceinline__ float wave_sum64(float x) {
#pragma unroll
  for (int off = 1; off < 64; off <<= 1) x += __shfl_xor(x, off, 64);
  return x;
}
__device__ __forceinline__ float wave_max64(float x) {
#pragma unroll
  for (int off = 1; off < 64; off <<= 1) x = fmaxf(x, __shfl_xor(x, off, 64));
  return x;
}
// 4 col-accumulators += one row-pair (16B of fp16) * y-pair, via v_dot2_f32_f16
__device__ __forceinline__ void fd4(float4 sv, half2_t yy,
                                    float& a0, float& a1, float& a2, float& a3) {
  H2x4 s; s.f4 = sv;
  a0 = __builtin_amdgcn_fdot2(s.h[0], yy, a0, false);
  a1 = __builtin_amdgcn_fdot2(s.h[1], yy, a1, false);
  a2 = __builtin_amdgcn_fdot2(s.h[2], yy, a2, false);
  a3 = __builtin_amdgcn_fdot2(s.h[3], yy, a3, false);
}

// ============ fp16 path ============
// ---- conversion: Sh[b][pair][col] = half2( sym(2p,col), sym(2p+1,col) ) ----
__global__ void sym_conv_kernel(const float* __restrict__ S, half2_t* __restrict__ Sh) {
  const int bb = blockIdx.x, ti = blockIdx.y, tj = blockIdx.z;
  if (tj < ti) return;
  __shared__ float ta[32][33];
  __shared__ float tb[32][33];
  const float* base = S + (size_t)bb * NDIM * NDIM;
  half2_t* dst = Sh + (size_t)bb * NPAIR * NDIM;
  const int tx = threadIdx.x, ty = threadIdx.y;  // 32 x 8
#pragma unroll
  for (int k = 0; k < 4; k++) {
    int r = ty + 8 * k;
    ta[r][tx] = base[(size_t)(ti * 32 + r) * NDIM + tj * 32 + tx];
    tb[r][tx] = base[(size_t)(tj * 32 + r) * NDIM + ti * 32 + tx];
  }
  __syncthreads();
#pragma unroll
  for (int k = 0; k < 2; k++) {
    int pi = ty + 8 * k;  // local pair 0..15
    float v0 = 0.5f * (ta[2 * pi][tx] + tb[tx][2 * pi]);
    float v1 = 0.5f * (ta[2 * pi + 1][tx] + tb[tx][2 * pi + 1]);
    half2_t o; o[0] = (_Float16)v0; o[1] = (_Float16)v1;
    dst[(size_t)(ti * 16 + pi) * NDIM + tj * 32 + tx] = o;
  }
  if (ti != tj) {
#pragma unroll
    for (int k = 0; k < 2; k++) {
      int pi = ty + 8 * k;
      float v0 = 0.5f * (tb[2 * pi][tx] + ta[tx][2 * pi]);
      float v1 = 0.5f * (tb[2 * pi + 1][tx] + ta[tx][2 * pi + 1]);
      half2_t o; o[0] = (_Float16)v0; o[1] = (_Float16)v1;
      dst[(size_t)(tj * 16 + pi) * NDIM + ti * 32 + tx] = o;
    }
  }
}

__device__ __forceinline__ void combine_z8(const float* __restrict__ zsc, int lane, float* z8) {
#pragma unroll
  for (int q = 0; q < 2; q++) {
    float4 zz = ld4(zsc + 8 * lane + 4 * q);
#pragma unroll
    for (int gg = 1; gg < 8; gg++)
      zz = f4_add(zz, ld4(zsc + gg * NDIM + 8 * lane + 4 * q));
    z8[4 * q + 0] = zz.x; z8[4 * q + 1] = zz.y;
    z8[4 * q + 2] = zz.z; z8[4 * q + 3] = zz.w;
  }
}

__device__ __forceinline__ void store_y_pairs(half2_t* ysh, int lane, const float* y8) {
  H2x4 yo;
#pragma unroll
  for (int q = 0; q < 4; q++) {
    half2_t v; v[0] = (_Float16)y8[2 * q]; v[1] = (_Float16)y8[2 * q + 1];
    yo.h[q] = v;
  }
  *(float4*)(ysh + 4 * lane) = yo.f4;
}

// Merged loop: iters [0,30) power, iter 30 = lambda/step, then FISTA.
// 1024 threads: 8 groups x 128; group owns 32 pairs; thread 32 pairs x 4 cols (512B).
// Residency per thread: 16 pairs regs (64 VGPR) + 8 pairs LDS + 8 pairs L2-streamed
// (two 4-deep batches, staggered so peak regs ~120 < 128 budget -> NO SPILL).
// (Resubmission of round-5 kernel: container-level infra failure, hypothesis untested.)
__global__ __launch_bounds__(1024)
void qp_solver_h(const float* __restrict__ mu,
                 const half2_t* __restrict__ Sh,
                 float* __restrict__ out) {
  __shared__ __align__(16) float4 lsm[8 * LDSP][128];  // 128 KB matrix slice
  __shared__ __align__(16) half2_t yh2[NPAIR];         // y as row-pairs (fp16), 1 KB
  __shared__ __align__(16) float zsc[8 * NDIM];        // matvec partials, 16 KB
  __shared__ int stopf;
  const int tid = threadIdx.x;
  const int g = tid >> 7;        // 8 groups x 128 threads; group owns 32 row-pairs
  const int c = tid & 127;       // cols 4c..4c+3
  const int b = blockIdx.x;
  const half2_t* Sb = Sh + (size_t)b * NPAIR * NDIM;
  const float invn = 1.0f / (float)NDIM;
  const half2_t* rp = Sb + (size_t)(32 * g) * NDIM + 4 * c;   // slab base
  const half2_t* gp = rp + (size_t)(REGK + LDSP) * NDIM;      // stream base (8 pairs)

  // register slab: pairs [0,16)
  float4 sreg[REGK];
#pragma unroll
  for (int p = 0; p < REGK; p++) sreg[p] = *(const float4*)(rp + (size_t)p * NDIM);
  // LDS slab: pairs [16,24)  (self-read only, no sync needed)
#pragma unroll
  for (int k = 0; k < LDSP; k++)
    lsm[g * LDSP + k][c] = *(const float4*)(rp + (size_t)(REGK + k) * NDIM);

  if (tid < NPAIR) { half2_t v; v[0] = (_Float16)invn; v[1] = (_Float16)invn; yh2[tid] = v; }
  if (tid == 0) stopf = 0;

  // wave0-only FISTA state (mu8 reloaded per-iter from hot L2 to save regs)
  float y8[8], w8[8];
  float t = 1.0f, step = 0.f, maxinc = 0.f;
  float th = -3e38f;             // warm-start simplex threshold
  if (tid < 64) {
#pragma unroll
    for (int k = 0; k < 8; k++) { y8[k] = invn; w8[k] = invn; }
  }
  __syncthreads();

  const int TOT = POWER_ITERS + 1 + N_ITERS;
  for (int it = 0; it < TOT; it++) {
    // ---------- matvec: z[4c..4c+3] partial over this group's 32 pairs ----------
    float a0 = 0.f, a1 = 0.f, a2 = 0.f, a3 = 0.f;
    {
      const half2_t* ybase = yh2 + 32 * g;
      float4 stA[4], stB[4];
      // batch A: stream pairs 24..27
#pragma unroll
      for (int k = 0; k < 4; k++) stA[k] = *(const float4*)(gp + (size_t)k * NDIM);
      // register slab pairs 0..7 (covers A's L2 latency)
#pragma unroll
      for (int ch = 0; ch < 2; ch++) {
        H2x4 y4; y4.f4 = *(const float4*)(ybase + 4 * ch);
#pragma unroll
        for (int q = 0; q < 4; q++) fd4(sreg[4 * ch + q], y4.h[q], a0, a1, a2, a3);
      }
      // batch B: stream pairs 28..31
#pragma unroll
      for (int k = 0; k < 4; k++) stB[k] = *(const float4*)(gp + (size_t)(4 + k) * NDIM);
      // register slab pairs 8..15
#pragma unroll
      for (int ch = 2; ch < 4; ch++) {
        H2x4 y4; y4.f4 = *(const float4*)(ybase + 4 * ch);
#pragma unroll
        for (int q = 0; q < 4; q++) fd4(sreg[4 * ch + q], y4.h[q], a0, a1, a2, a3);
      }
      // consume A
      {
        H2x4 y4; y4.f4 = *(const float4*)(ybase + REGK + LDSP);
#pragma unroll
        for (int k = 0; k < 4; k++) fd4(stA[k], y4.h[k], a0, a1, a2, a3);
      }
      // LDS slab pairs 16..23 (covers B's latency)
#pragma unroll
      for (int ch = 0; ch < 2; ch++) {
        H2x4 y4; y4.f4 = *(const float4*)(ybase + REGK + 4 * ch);
#pragma unroll
        for (int q = 0; q < 4; q++)
          fd4(lsm[g * LDSP + 4 * ch + q][c], y4.h[q], a0, a1, a2, a3);
      }
      // consume B
      {
        H2x4 y4; y4.f4 = *(const float4*)(ybase + REGK + LDSP + 4);
#pragma unroll
        for (int k = 0; k < 4; k++) fd4(stB[k], y4.h[k], a0, a1, a2, a3);
      }
    }
    *(float4*)(zsc + g * NDIM + 4 * c) = make_float4(a0, a1, a2, a3);
    __syncthreads();

    // ---------- serial phase (wave 0) ----------
    if (tid < 64) {
      // mu reload issued first, overlaps combine's LDS reads (FISTA only)
      float mu8[8];
      if (it > POWER_ITERS) {
        float4 m0 = ld4(mu + (size_t)b * NDIM + 8 * tid);
        float4 m1 = ld4(mu + (size_t)b * NDIM + 8 * tid + 4);
        mu8[0] = m0.x; mu8[1] = m0.y; mu8[2] = m0.z; mu8[3] = m0.w;
        mu8[4] = m1.x; mu8[5] = m1.y; mu8[6] = m1.z; mu8[7] = m1.w;
      }
      float z8[8];
      combine_z8(zsc, tid, z8);
      if (it < POWER_ITERS) {
        float ss = 0.f;
#pragma unroll
        for (int k = 0; k < 8; k++) ss += z8[k] * z8[k];
        ss = wave_sum64(ss);
        float inv = 1.0f / (sqrtf(ss) + 1e-12f);
#pragma unroll
        for (int k = 0; k < 8; k++) y8[k] = z8[k] * inv;
        store_y_pairs(yh2, tid, y8);
      } else if (it == POWER_ITERS) {
        float dd = 0.f;
#pragma unroll
        for (int k = 0; k < 8; k++) dd += z8[k] * y8[k];
        dd = wave_sum64(dd);
        step = 1.0f / (2.0f * dd + 1e-8f);
#pragma unroll
        for (int k = 0; k < 8; k++) { y8[k] = invn; w8[k] = invn; }
        t = 1.0f; maxinc = 0.f;
        store_y_pairs(yh2, tid, y8);
      } else {
        float v8[8];
#pragma unroll
        for (int k = 0; k < 8; k++)
          v8[k] = y8[k] - step * (2.0f * z8[k] - mu8[k]);

        // ---- warm-started two-sided Michelot simplex projection ----
        {
          float s = 0.f, cn = 0.f, stot = 0.f;
#pragma unroll
          for (int k = 0; k < 8; k++) {
            stot += v8[k];
            if (v8[k] > th) { s += v8[k]; cn += 1.f; }
          }
#pragma unroll
          for (int off = 1; off < 64; off <<= 1) {
            s    += __shfl_xor(s, off, 64);
            cn   += __shfl_xor(cn, off, 64);
            stot += __shfl_xor(stot, off, 64);
          }
          th = (cn > 0.f) ? (s - 1.0f) / cn
                          : (stot - 1.0f) * (1.0f / 512.0f);  // guard: empty set
        }
        // from-below fixed-point iterations (typically 1-2 near convergence)
        for (int m = 0; m < 16; m++) {
          float s = 0.f, cn = 0.f;
#pragma unroll
          for (int k = 0; k < 8; k++)
            if (v8[k] > th) { s += v8[k]; cn += 1.f; }
#pragma unroll
          for (int off = 1; off < 64; off <<= 1) {
            s  += __shfl_xor(s, off, 64);
            cn += __shfl_xor(cn, off, 64);
          }
          float thn = (s - 1.0f) / cn;
          if (!(thn > th)) break;
          th = thn;
        }

        float tn = 0.5f * (1.0f + sqrtf(1.0f + 4.0f * t * t));
        float coef = (t - 1.0f) / tn;
#pragma unroll
        for (int k = 0; k < 8; k++) {
          float wn = fmaxf(v8[k] - th, 0.0f);
          maxinc = fmaxf(maxinc, fabsf(wn - w8[k]));
          y8[k] = wn + coef * (wn - w8[k]);
          w8[k] = wn;
        }
        t = tn;
        store_y_pairs(yh2, tid, y8);
        // convergence reduce amortized over 4 iterations
        if ((it & 3) == 3) {
          float mi = wave_max64(maxinc);
          if (tid == 0) stopf = (mi < 1e-7f) ? (stopf + 1) : 0;
          maxinc = 0.f;
        }
      }
    }
    __syncthreads();
    if (stopf >= 2) break;
  }

  if (tid < 64) {
    *(float4*)(out + (size_t)b * NDIM + 8 * tid)     = make_float4(w8[0], w8[1], w8[2], w8[3]);
    *(float4*)(out + (size_t)b * NDIM + 8 * tid + 4) = make_float4(w8[4], w8[5], w8[6], w8[7]);
  }
}

// ============ fp32 fallback path (used only if ws too small) ============
__global__ void symmetrize_kernel(float* __restrict__ S) {
  const int ti = blockIdx.y, tj = blockIdx.z;
  if (tj < ti) return;
  __shared__ float ta[32][33];
  __shared__ float tb[32][33];
  float* base = S + (size_t)blockIdx.x * NDIM * NDIM;
  const int tx = threadIdx.x, ty = threadIdx.y;
#pragma unroll
  for (int k = 0; k < 4; k++) {
    int r = ty + 8 * k;
    ta[r][tx] = base[(size_t)(ti * 32 + r) * NDIM + tj * 32 + tx];
    tb[r][tx] = base[(size_t)(tj * 32 + r) * NDIM + ti * 32 + tx];
  }
  __syncthreads();
#pragma unroll
  for (int k = 0; k < 4; k++) {
    int r = ty + 8 * k;
    base[(size_t)(ti * 32 + r) * NDIM + tj * 32 + tx] = 0.5f * (ta[r][tx] + tb[tx][r]);
  }
#pragma unroll
  for (int k = 0; k < 4; k++) {
    int r = ty + 8 * k;
    base[(size_t)(tj * 32 + r) * NDIM + ti * 32 + tx] = 0.5f * (tb[r][tx] + ta[tx][r]);
  }
}

__device__ __forceinline__ float4 f4_fma(float4 a, float s, float4 acc) {
  acc.x = fmaf(a.x, s, acc.x); acc.y = fmaf(a.y, s, acc.y);
  acc.z = fmaf(a.z, s, acc.z); acc.w = fmaf(a.w, s, acc.w);
  return acc;
}
__device__ __forceinline__ void combine_z(const float* __restrict__ zsc, int lane, float* z8) {
#pragma unroll
  for (int q = 0; q < 2; q++) {
    float4 zz = ld4(zsc + 0 * NDIM + 8 * lane + 4 * q);
    zz = f4_add(zz, ld4(zsc + 1 * NDIM + 8 * lane + 4 * q));
    zz = f4_add(zz, ld4(zsc + 2 * NDIM + 8 * lane + 4 * q));
    zz = f4_add(zz, ld4(zsc + 3 * NDIM + 8 * lane + 4 * q));
    z8[4 * q + 0] = zz.x; z8[4 * q + 1] = zz.y;
    z8[4 * q + 2] = zz.z; z8[4 * q + 3] = zz.w;
  }
}
__device__ __forceinline__ void matvec_partial(const float* __restrict__ Sb,
                                               const float* __restrict__ yv,
                                               float* __restrict__ zsc, int g, int c) {
  const float* rp = Sb + (size_t)(g * 128) * NDIM + 4 * c;
  const float* yp = yv + g * 128;
  float4 a0 = make_float4(0, 0, 0, 0), a1 = a0, a2 = a0, a3 = a0;
#pragma unroll 4
  for (int m = 0; m < 32; m++) {
    float4 yq = ld4(yp + 4 * m);
    float4 s0 = ld4(rp + (size_t)(4 * m + 0) * NDIM);
    float4 s1 = ld4(rp + (size_t)(4 * m + 1) * NDIM);
    float4 s2 = ld4(rp + (size_t)(4 * m + 2) * NDIM);
    float4 s3 = ld4(rp + (size_t)(4 * m + 3) * NDIM);
    a0 = f4_fma(s0, yq.x, a0); a1 = f4_fma(s1, yq.y, a1);
    a2 = f4_fma(s2, yq.z, a2); a3 = f4_fma(s3, yq.w, a3);
  }
  float4 z = f4_add(f4_add(a0, a1), f4_add(a2, a3));
  *(float4*)(zsc + g * NDIM + 4 * c) = z;
}

__launch_bounds__(512, 1)
__global__ void qp_solver(const float* __restrict__ mu,
                          const float* __restrict__ S,
                          float* __restrict__ out) {
  __shared__ float yv[NDIM];
  __shared__ float zsc[4 * NDIM];
  __shared__ float bc[1];
  const int tid = threadIdx.x, g = tid >> 7, c = tid & 127, b = blockIdx.x;
  const float* Sb = S + (size_t)b * NDIM * NDIM;
  const float invn = 1.0f / (float)NDIM;
  yv[tid] = invn;
  __syncthreads();
  for (int it = 0; it < POWER_ITERS; it++) {
    matvec_partial(Sb, yv, zsc, g, c);
    __syncthreads();
    if (tid < 64) {
      float z8[8]; combine_z(zsc, tid, z8);
      float ss = 0.f;
#pragma unroll
      for (int k = 0; k < 8; k++) ss += z8[k] * z8[k];
      ss = wave_sum64(ss);
      float inv = 1.0f / (sqrtf(ss) + 1e-12f);
      *(float4*)(yv + 8 * tid)     = make_float4(z8[0]*inv, z8[1]*inv, z8[2]*inv, z8[3]*inv);
      *(float4*)(yv + 8 * tid + 4) = make_float4(z8[4]*inv, z8[5]*inv, z8[6]*inv, z8[7]*inv);
    }
    __syncthreads();
  }
  matvec_partial(Sb, yv, zsc, g, c);
  __syncthreads();
  if (tid < 64) {
    float z8[8]; combine_z(zsc, tid, z8);
    float dd = 0.f;
#pragma unroll
    for (int k = 0; k < 8; k++) dd += z8[k] * yv[8 * tid + k];
    dd = wave_sum64(dd);
    if (tid == 0) bc[0] = 1.0f / (2.0f * dd + 1e-8f);
  }
  __syncthreads();
  const float step = bc[0];
  yv[tid] = invn;
  float w8[8], y8[8], mu8[8];
  if (tid < 64) {
#pragma unroll
    for (int k = 0; k < 8; k++) { w8[k] = invn; y8[k] = invn; }
    float4 m0 = ld4(mu + (size_t)b * NDIM + 8 * tid);
    float4 m1 = ld4(mu + (size_t)b * NDIM + 8 * tid + 4);
    mu8[0] = m0.x; mu8[1] = m0.y; mu8[2] = m0.z; mu8[3] = m0.w;
    mu8[4] = m1.x; mu8[5] = m1.y; mu8[6] = m1.z; mu8[7] = m1.w;
  }
  __syncthreads();
  float t = 1.0f;
  for (int it = 0; it < N_ITERS; it++) {
    matvec_partial(Sb, yv, zsc, g, c);
    __syncthreads();
    if (tid < 64) {
      float z8[8], v8[8]; combine_z(zsc, tid, z8);
#pragma unroll
      for (int k = 0; k < 8; k++) v8[k] = y8[k] - step * (2.0f * z8[k] - mu8[k]);
      float th = -1e30f;
      for (int m = 0; m < 64; m++) {
        float s = 0.f, cn = 0.f;
#pragma unroll
        for (int k = 0; k < 8; k++) if (v8[k] > th) { s += v8[k]; cn += 1.f; }
#pragma unroll
        for (int off = 1; off < 64; off <<= 1) { s += __shfl_xor(s, off, 64); cn += __shfl_xor(cn, off, 64); }
        float thn = (s - 1.0f) / cn;
        if (!(thn > th)) break;
        th = thn;
      }
      float tn = 0.5f * (1.0f + sqrtf(1.0f + 4.0f * t * t));
      float coef = (t - 1.0f) / tn;
#pragma unroll
      for (int k = 0; k < 8; k++) {
        float wn = fmaxf(v8[k] - th, 0.0f);
        y8[k] = wn + coef * (wn - w8[k]);
        w8[k] = wn;
      }
      *(float4*)(yv + 8 * tid)     = make_float4(y8[0], y8[1], y8[2], y8[3]);
      *(float4*)(yv + 8 * tid + 4) = make_float4(y8[4], y8[5], y8[6], y8[7]);
      t = tn;
    }
    __syncthreads();
  }
  if (tid < 64) {
    *(float4*)(out + (size_t)b * NDIM + 8 * tid)     = make_float4(w8[0], w8[1], w8[2], w8[3]);
    *(float4*)(out + (size_t)b * NDIM + 8 * tid + 4) = make_float4(w8[4], w8[5], w8[6], w8[7]);
  }
}

// ---------------- launch ----------------
extern "C" void kernel_launch(void* const* d_in, const int* in_sizes, int n_in,
                              void* d_out, int out_size, void* d_ws, size_t ws_size,
                              hipStream_t stream) {
  const float* mu = (const float*)d_in[0];
  float* Sg = (float*)d_in[1];
  if (n_in >= 2 && in_sizes[0] > in_sizes[1]) { mu = (const float*)d_in[1]; Sg = (float*)d_in[0]; }
  float* out = (float*)d_out;

  const size_t need = (size_t)BATCH * NPAIR * NDIM * sizeof(half2_t);  // 64 MB
  if (ws_size >= need) {
    half2_t* Sh = (half2_t*)d_ws;
    sym_conv_kernel<<<dim3(BATCH, 16, 16), dim3(32, 8), 0, stream>>>(Sg, Sh);
    qp_solver_h<<<dim3(BATCH), dim3(1024), 0, stream>>>(mu, Sh, out);
  } else {
    symmetrize_kernel<<<dim3(BATCH, 16, 16), dim3(32, 8), 0, stream>>>(Sg);
    qp_solver<<<dim3(BATCH), dim3(512), 0, stream>>>(mu, Sg, out);
  }
}

// Round 8
// 1833.932 us; speedup vs baseline: 1.6095x; 1.6095x over previous
//
#include <hip/hip_runtime.h>
#include <hip/hip_fp16.h>
#include <math.h>

#define BATCH 128
#define NDIM 512
#define NPAIR 256          // row-pairs per batch
#define POWER_ITERS 30
#define N_ITERS 500
// 512 threads = 4 groups x 128; group owns 64 pairs; thread: 64 pairs x 4 cols.
#define REGK 16            // pairs in registers (64 VGPR, honest fit at 128 budget)
#define LDSP 16            // pairs in LDS (4 groups x 16 x 2KB = 128 KB)
#define STRM 32            // pairs streamed from L2, 8 chunks of 4, sparsity-masked

typedef _Float16 half2_t __attribute__((ext_vector_type(2)));

union H2x4 { float4 f4; half2_t h[4]; };

// ---------------- helpers ----------------
__device__ __forceinline__ float4 ld4(const float* p) { return *(const float4*)p; }
__device__ __forceinline__ float4 f4_add(float4 a, float4 b) {
  return make_float4(a.x + b.x, a.y + b.y, a.z + b.z, a.w + b.w);
}
__device__ __forceinline__ float wave_sum64(float x) {
#pragma unroll
  for (int off = 1; off < 64; off <<= 1) x += __shfl_xor(x, off, 64);
  return x;
}
__device__ __forceinline__ float wave_max64(float x) {
#pragma unroll
  for (int off = 1; off < 64; off <<= 1) x = fmaxf(x, __shfl_xor(x, off, 64));
  return x;
}
// 4 col-accumulators += one row-pair (16B of fp16) * y-pair, via v_dot2_f32_f16
__device__ __forceinline__ void fd4(float4 sv, half2_t yy,
                                    float& a0, float& a1, float& a2, float& a3) {
  H2x4 s; s.f4 = sv;
  a0 = __builtin_amdgcn_fdot2(s.h[0], yy, a0, false);
  a1 = __builtin_amdgcn_fdot2(s.h[1], yy, a1, false);
  a2 = __builtin_amdgcn_fdot2(s.h[2], yy, a2, false);
  a3 = __builtin_amdgcn_fdot2(s.h[3], yy, a3, false);
}

// ============ fp16 path ============
// ---- conversion: Sh[b][pair][col] = half2( sym(2p,col), sym(2p+1,col) ) ----
__global__ void sym_conv_kernel(const float* __restrict__ S, half2_t* __restrict__ Sh) {
  const int bb = blockIdx.x, ti = blockIdx.y, tj = blockIdx.z;
  if (tj < ti) return;
  __shared__ float ta[32][33];
  __shared__ float tb[32][33];
  const float* base = S + (size_t)bb * NDIM * NDIM;
  half2_t* dst = Sh + (size_t)bb * NPAIR * NDIM;
  const int tx = threadIdx.x, ty = threadIdx.y;  // 32 x 8
#pragma unroll
  for (int k = 0; k < 4; k++) {
    int r = ty + 8 * k;
    ta[r][tx] = base[(size_t)(ti * 32 + r) * NDIM + tj * 32 + tx];
    tb[r][tx] = base[(size_t)(tj * 32 + r) * NDIM + ti * 32 + tx];
  }
  __syncthreads();
#pragma unroll
  for (int k = 0; k < 2; k++) {
    int pi = ty + 8 * k;  // local pair 0..15
    float v0 = 0.5f * (ta[2 * pi][tx] + tb[tx][2 * pi]);
    float v1 = 0.5f * (ta[2 * pi + 1][tx] + tb[tx][2 * pi + 1]);
    half2_t o; o[0] = (_Float16)v0; o[1] = (_Float16)v1;
    dst[(size_t)(ti * 16 + pi) * NDIM + tj * 32 + tx] = o;
  }
  if (ti != tj) {
#pragma unroll
    for (int k = 0; k < 2; k++) {
      int pi = ty + 8 * k;
      float v0 = 0.5f * (tb[2 * pi][tx] + ta[tx][2 * pi]);
      float v1 = 0.5f * (tb[2 * pi + 1][tx] + ta[tx][2 * pi + 1]);
      half2_t o; o[0] = (_Float16)v0; o[1] = (_Float16)v1;
      dst[(size_t)(tj * 16 + pi) * NDIM + ti * 32 + tx] = o;
    }
  }
}

__device__ __forceinline__ void combine_z(const float* __restrict__ zsc, int lane, float* z8) {
#pragma unroll
  for (int q = 0; q < 2; q++) {
    float4 zz = ld4(zsc + 0 * NDIM + 8 * lane + 4 * q);
    zz = f4_add(zz, ld4(zsc + 1 * NDIM + 8 * lane + 4 * q));
    zz = f4_add(zz, ld4(zsc + 2 * NDIM + 8 * lane + 4 * q));
    zz = f4_add(zz, ld4(zsc + 3 * NDIM + 8 * lane + 4 * q));
    z8[4 * q + 0] = zz.x; z8[4 * q + 1] = zz.y;
    z8[4 * q + 2] = zz.z; z8[4 * q + 3] = zz.w;
  }
}

__device__ __forceinline__ void store_y_pairs(half2_t* ysh, int lane, const float* y8) {
  H2x4 yo;
#pragma unroll
  for (int q = 0; q < 4; q++) {
    half2_t v; v[0] = (_Float16)y8[2 * q]; v[1] = (_Float16)y8[2 * q + 1];
    yo.h[q] = v;
  }
  *(float4*)(ysh + 4 * lane) = yo.f4;
}

// Merged loop: iters [0,30) power, iter 30 = lambda/step, then FISTA.
// Residency per thread (owns 64 pairs x 4 cols):
//   pairs  0..15 -> registers (honest fit: 64 data VGPR at the immovable 128 budget)
//   pairs 16..31 -> LDS (128 KB, self-read only)
//   pairs 32..63 -> streamed from L2 in 8 chunks of 4 pairs, SPARSITY-MASKED:
//     chunks whose 4 y-pairs are all exactly +0 (fp16) are skipped entirely --
//     bit-exact (fdot2 with zero y adds exactly 0), and the mask is uniform
//     across the group's 128 threads so the branch is cheap s_cbranch.
__global__ __launch_bounds__(512)
void qp_solver_h(const float* __restrict__ mu,
                 const half2_t* __restrict__ Sh,
                 float* __restrict__ out) {
  __shared__ __align__(16) float4 lsm[4 * LDSP][128];  // 128 KB matrix slice
  __shared__ __align__(16) half2_t yh2[NPAIR];         // y as row-pairs (fp16)
  __shared__ __align__(16) float zsc[4 * NDIM];        // matvec partials per group
  __shared__ int stopf;
  const int tid = threadIdx.x;
  const int g = tid >> 7;        // 4 groups x 128 threads; group owns 64 row-pairs
  const int c = tid & 127;       // cols 4c..4c+3
  const int b = blockIdx.x;
  const half2_t* Sb = Sh + (size_t)b * NPAIR * NDIM;
  const float invn = 1.0f / (float)NDIM;
  const half2_t* rp = Sb + (size_t)(64 * g) * NDIM + 4 * c;   // slab base
  const half2_t* gp = rp + (size_t)(REGK + LDSP) * NDIM;      // stream base (32 pairs)

  // register slab: pairs [0,16)
  float4 sreg[REGK];
#pragma unroll
  for (int p = 0; p < REGK; p++) sreg[p] = *(const float4*)(rp + (size_t)p * NDIM);
  // LDS slab: pairs [16,32)  (self-read only, no sync needed)
#pragma unroll
  for (int k = 0; k < LDSP; k++)
    lsm[g * LDSP + k][c] = *(const float4*)(rp + (size_t)(REGK + k) * NDIM);

  if (tid < NPAIR) { half2_t v; v[0] = (_Float16)invn; v[1] = (_Float16)invn; yh2[tid] = v; }
  if (tid == 0) stopf = 0;

  // wave0-only FISTA state (mu8 reloaded per-iter from hot L2 to save regs)
  float y8[8], w8[8];
  float t = 1.0f, step = 0.f, maxinc = 0.f;
  float th = -3e38f;             // warm-start simplex threshold
  if (tid < 64) {
#pragma unroll
    for (int k = 0; k < 8; k++) { y8[k] = invn; w8[k] = invn; }
  }
  __syncthreads();

  const int TOT = POWER_ITERS + 1 + N_ITERS;
  for (int it = 0; it < TOT; it++) {
    // ---------- matvec: z[4c..4c+3] partial over this group's 64 pairs ----------
    float a0 = 0.f, a1 = 0.f, a2 = 0.f, a3 = 0.f;
    {
      const half2_t* ybase = yh2 + 64 * g;
      // activity mask over the 8 streamed chunks (pairs 32+4j..32+4j+3)
      unsigned m = 0;
#pragma unroll
      for (int j = 0; j < 8; j++) {
        const uint4 u = *(const uint4*)(ybase + REGK + LDSP + 4 * j);
        m |= ((u.x | u.y | u.z | u.w) != 0u ? 1u : 0u) << j;
      }
      float4 stA[4], stB[4];
      // issue chunks 0,1
      if (m & 1u) {
#pragma unroll
        for (int k = 0; k < 4; k++) stA[k] = *(const float4*)(gp + (size_t)(0 + k) * NDIM);
      }
      if (m & 2u) {
#pragma unroll
        for (int k = 0; k < 4; k++) stB[k] = *(const float4*)(gp + (size_t)(4 + k) * NDIM);
      }
      // register slab pairs 0..15 (64 fdot2) -- covers chunk 0/1 latency
#pragma unroll
      for (int ch = 0; ch < REGK / 4; ch++) {
        H2x4 y4; y4.f4 = *(const float4*)(ybase + 4 * ch);
#pragma unroll
        for (int q = 0; q < 4; q++) fd4(sreg[4 * ch + q], y4.h[q], a0, a1, a2, a3);
      }
      // consume 0, issue 2
      if (m & 1u) {
        H2x4 y4; y4.f4 = *(const float4*)(ybase + REGK + LDSP + 0);
#pragma unroll
        for (int k = 0; k < 4; k++) fd4(stA[k], y4.h[k], a0, a1, a2, a3);
      }
      if (m & 4u) {
#pragma unroll
        for (int k = 0; k < 4; k++) stA[k] = *(const float4*)(gp + (size_t)(8 + k) * NDIM);
      }
      // LDS slab pairs 16..23 -- covers chunk 2 latency
#pragma unroll
      for (int ch = 0; ch < 2; ch++) {
        H2x4 y4; y4.f4 = *(const float4*)(ybase + REGK + 4 * ch);
#pragma unroll
        for (int q = 0; q < 4; q++)
          fd4(lsm[g * LDSP + 4 * ch + q][c], y4.h[q], a0, a1, a2, a3);
      }
      // consume 1, issue 3
      if (m & 2u) {
        H2x4 y4; y4.f4 = *(const float4*)(ybase + REGK + LDSP + 4);
#pragma unroll
        for (int k = 0; k < 4; k++) fd4(stB[k], y4.h[k], a0, a1, a2, a3);
      }
      if (m & 8u) {
#pragma unroll
        for (int k = 0; k < 4; k++) stB[k] = *(const float4*)(gp + (size_t)(12 + k) * NDIM);
      }
      // LDS slab pairs 24..31 -- covers chunk 3 latency
#pragma unroll
      for (int ch = 2; ch < 4; ch++) {
        H2x4 y4; y4.f4 = *(const float4*)(ybase + REGK + 4 * ch);
#pragma unroll
        for (int q = 0; q < 4; q++)
          fd4(lsm[g * LDSP + 4 * ch + q][c], y4.h[q], a0, a1, a2, a3);
      }
      // tail ladder: consume k, issue k+2
      if (m & 4u) {
        H2x4 y4; y4.f4 = *(const float4*)(ybase + REGK + LDSP + 8);
#pragma unroll
        for (int k = 0; k < 4; k++) fd4(stA[k], y4.h[k], a0, a1, a2, a3);
      }
      if (m & 16u) {
#pragma unroll
        for (int k = 0; k < 4; k++) stA[k] = *(const float4*)(gp + (size_t)(16 + k) * NDIM);
      }
      if (m & 8u) {
        H2x4 y4; y4.f4 = *(const float4*)(ybase + REGK + LDSP + 12);
#pragma unroll
        for (int k = 0; k < 4; k++) fd4(stB[k], y4.h[k], a0, a1, a2, a3);
      }
      if (m & 32u) {
#pragma unroll
        for (int k = 0; k < 4; k++) stB[k] = *(const float4*)(gp + (size_t)(20 + k) * NDIM);
      }
      if (m & 16u) {
        H2x4 y4; y4.f4 = *(const float4*)(ybase + REGK + LDSP + 16);
#pragma unroll
        for (int k = 0; k < 4; k++) fd4(stA[k], y4.h[k], a0, a1, a2, a3);
      }
      if (m & 64u) {
#pragma unroll
        for (int k = 0; k < 4; k++) stA[k] = *(const float4*)(gp + (size_t)(24 + k) * NDIM);
      }
      if (m & 32u) {
        H2x4 y4; y4.f4 = *(const float4*)(ybase + REGK + LDSP + 20);
#pragma unroll
        for (int k = 0; k < 4; k++) fd4(stB[k], y4.h[k], a0, a1, a2, a3);
      }
      if (m & 128u) {
#pragma unroll
        for (int k = 0; k < 4; k++) stB[k] = *(const float4*)(gp + (size_t)(28 + k) * NDIM);
      }
      if (m & 64u) {
        H2x4 y4; y4.f4 = *(const float4*)(ybase + REGK + LDSP + 24);
#pragma unroll
        for (int k = 0; k < 4; k++) fd4(stA[k], y4.h[k], a0, a1, a2, a3);
      }
      if (m & 128u) {
        H2x4 y4; y4.f4 = *(const float4*)(ybase + REGK + LDSP + 28);
#pragma unroll
        for (int k = 0; k < 4; k++) fd4(stB[k], y4.h[k], a0, a1, a2, a3);
      }
    }
    *(float4*)(zsc + g * NDIM + 4 * c) = make_float4(a0, a1, a2, a3);
    __syncthreads();

    // ---------- serial phase (wave 0) ----------
    if (tid < 64) {
      // mu reload issued first, overlaps combine's LDS reads (FISTA only)
      float mu8[8];
      if (it > POWER_ITERS) {
        float4 m0 = ld4(mu + (size_t)b * NDIM + 8 * tid);
        float4 m1 = ld4(mu + (size_t)b * NDIM + 8 * tid + 4);
        mu8[0] = m0.x; mu8[1] = m0.y; mu8[2] = m0.z; mu8[3] = m0.w;
        mu8[4] = m1.x; mu8[5] = m1.y; mu8[6] = m1.z; mu8[7] = m1.w;
      }
      float z8[8];
      combine_z(zsc, tid, z8);
      if (it < POWER_ITERS) {
        float ss = 0.f;
#pragma unroll
        for (int k = 0; k < 8; k++) ss += z8[k] * z8[k];
        ss = wave_sum64(ss);
        float inv = 1.0f / (sqrtf(ss) + 1e-12f);
#pragma unroll
        for (int k = 0; k < 8; k++) y8[k] = z8[k] * inv;
        store_y_pairs(yh2, tid, y8);
      } else if (it == POWER_ITERS) {
        float dd = 0.f;
#pragma unroll
        for (int k = 0; k < 8; k++) dd += z8[k] * y8[k];
        dd = wave_sum64(dd);
        step = 1.0f / (2.0f * dd + 1e-8f);
#pragma unroll
        for (int k = 0; k < 8; k++) { y8[k] = invn; w8[k] = invn; }
        t = 1.0f; maxinc = 0.f;
        store_y_pairs(yh2, tid, y8);
      } else {
        float v8[8];
#pragma unroll
        for (int k = 0; k < 8; k++)
          v8[k] = y8[k] - step * (2.0f * z8[k] - mu8[k]);

        // ---- warm-started two-sided Michelot simplex projection ----
        {
          float s = 0.f, cn = 0.f, stot = 0.f;
#pragma unroll
          for (int k = 0; k < 8; k++) {
            stot += v8[k];
            if (v8[k] > th) { s += v8[k]; cn += 1.f; }
          }
#pragma unroll
          for (int off = 1; off < 64; off <<= 1) {
            s    += __shfl_xor(s, off, 64);
            cn   += __shfl_xor(cn, off, 64);
            stot += __shfl_xor(stot, off, 64);
          }
          th = (cn > 0.f) ? (s - 1.0f) / cn
                          : (stot - 1.0f) * (1.0f / 512.0f);  // guard: empty set
        }
        // from-below fixed-point iterations (typically 1-2 near convergence)
        for (int m2 = 0; m2 < 16; m2++) {
          float s = 0.f, cn = 0.f;
#pragma unroll
          for (int k = 0; k < 8; k++)
            if (v8[k] > th) { s += v8[k]; cn += 1.f; }
#pragma unroll
          for (int off = 1; off < 64; off <<= 1) {
            s  += __shfl_xor(s, off, 64);
            cn += __shfl_xor(cn, off, 64);
          }
          float thn = (s - 1.0f) / cn;
          if (!(thn > th)) break;
          th = thn;
        }

        float tn = 0.5f * (1.0f + sqrtf(1.0f + 4.0f * t * t));
        float coef = (t - 1.0f) / tn;
#pragma unroll
        for (int k = 0; k < 8; k++) {
          float wn = fmaxf(v8[k] - th, 0.0f);
          maxinc = fmaxf(maxinc, fabsf(wn - w8[k]));
          y8[k] = wn + coef * (wn - w8[k]);
          w8[k] = wn;
        }
        t = tn;
        store_y_pairs(yh2, tid, y8);
        // convergence reduce amortized over 4 iterations
        if ((it & 3) == 3) {
          float mi = wave_max64(maxinc);
          if (tid == 0) stopf = (mi < 1e-7f) ? (stopf + 1) : 0;
          maxinc = 0.f;
        }
      }
    }
    __syncthreads();
    if (stopf >= 2) break;
  }

  if (tid < 64) {
    *(float4*)(out + (size_t)b * NDIM + 8 * tid)     = make_float4(w8[0], w8[1], w8[2], w8[3]);
    *(float4*)(out + (size_t)b * NDIM + 8 * tid + 4) = make_float4(w8[4], w8[5], w8[6], w8[7]);
  }
}

// ============ fp32 fallback path (used only if ws too small) ============
__global__ void symmetrize_kernel(float* __restrict__ S) {
  const int ti = blockIdx.y, tj = blockIdx.z;
  if (tj < ti) return;
  __shared__ float ta[32][33];
  __shared__ float tb[32][33];
  float* base = S + (size_t)blockIdx.x * NDIM * NDIM;
  const int tx = threadIdx.x, ty = threadIdx.y;
#pragma unroll
  for (int k = 0; k < 4; k++) {
    int r = ty + 8 * k;
    ta[r][tx] = base[(size_t)(ti * 32 + r) * NDIM + tj * 32 + tx];
    tb[r][tx] = base[(size_t)(tj * 32 + r) * NDIM + ti * 32 + tx];
  }
  __syncthreads();
#pragma unroll
  for (int k = 0; k < 4; k++) {
    int r = ty + 8 * k;
    base[(size_t)(ti * 32 + r) * NDIM + tj * 32 + tx] = 0.5f * (ta[r][tx] + tb[tx][r]);
  }
#pragma unroll
  for (int k = 0; k < 4; k++) {
    int r = ty + 8 * k;
    base[(size_t)(tj * 32 + r) * NDIM + ti * 32 + tx] = 0.5f * (tb[r][tx] + ta[tx][r]);
  }
}

__device__ __forceinline__ float4 f4_fma(float4 a, float s, float4 acc) {
  acc.x = fmaf(a.x, s, acc.x); acc.y = fmaf(a.y, s, acc.y);
  acc.z = fmaf(a.z, s, acc.z); acc.w = fmaf(a.w, s, acc.w);
  return acc;
}
__device__ __forceinline__ void matvec_partial(const float* __restrict__ Sb,
                                               const float* __restrict__ yv,
                                               float* __restrict__ zsc, int g, int c) {
  const float* rp = Sb + (size_t)(g * 128) * NDIM + 4 * c;
  const float* yp = yv + g * 128;
  float4 a0 = make_float4(0, 0, 0, 0), a1 = a0, a2 = a0, a3 = a0;
#pragma unroll 4
  for (int m = 0; m < 32; m++) {
    float4 yq = ld4(yp + 4 * m);
    float4 s0 = ld4(rp + (size_t)(4 * m + 0) * NDIM);
    float4 s1 = ld4(rp + (size_t)(4 * m + 1) * NDIM);
    float4 s2 = ld4(rp + (size_t)(4 * m + 2) * NDIM);
    float4 s3 = ld4(rp + (size_t)(4 * m + 3) * NDIM);
    a0 = f4_fma(s0, yq.x, a0); a1 = f4_fma(s1, yq.y, a1);
    a2 = f4_fma(s2, yq.z, a2); a3 = f4_fma(s3, yq.w, a3);
  }
  float4 z = f4_add(f4_add(a0, a1), f4_add(a2, a3));
  *(float4*)(zsc + g * NDIM + 4 * c) = z;
}

__launch_bounds__(512, 1)
__global__ void qp_solver(const float* __restrict__ mu,
                          const float* __restrict__ S,
                          float* __restrict__ out) {
  __shared__ float yv[NDIM];
  __shared__ float zsc[4 * NDIM];
  __shared__ float bc[1];
  const int tid = threadIdx.x, g = tid >> 7, c = tid & 127, b = blockIdx.x;
  const float* Sb = S + (size_t)b * NDIM * NDIM;
  const float invn = 1.0f / (float)NDIM;
  yv[tid] = invn;
  __syncthreads();
  for (int it = 0; it < POWER_ITERS; it++) {
    matvec_partial(Sb, yv, zsc, g, c);
    __syncthreads();
    if (tid < 64) {
      float z8[8]; combine_z(zsc, tid, z8);
      float ss = 0.f;
#pragma unroll
      for (int k = 0; k < 8; k++) ss += z8[k] * z8[k];
      ss = wave_sum64(ss);
      float inv = 1.0f / (sqrtf(ss) + 1e-12f);
      *(float4*)(yv + 8 * tid)     = make_float4(z8[0]*inv, z8[1]*inv, z8[2]*inv, z8[3]*inv);
      *(float4*)(yv + 8 * tid + 4) = make_float4(z8[4]*inv, z8[5]*inv, z8[6]*inv, z8[7]*inv);
    }
    __syncthreads();
  }
  matvec_partial(Sb, yv, zsc, g, c);
  __syncthreads();
  if (tid < 64) {
    float z8[8]; combine_z(zsc, tid, z8);
    float dd = 0.f;
#pragma unroll
    for (int k = 0; k < 8; k++) dd += z8[k] * yv[8 * tid + k];
    dd = wave_sum64(dd);
    if (tid == 0) bc[0] = 1.0f / (2.0f * dd + 1e-8f);
  }
  __syncthreads();
  const float step = bc[0];
  yv[tid] = invn;
  float w8[8], y8[8], mu8[8];
  if (tid < 64) {
#pragma unroll
    for (int k = 0; k < 8; k++) { w8[k] = invn; y8[k] = invn; }
    float4 m0 = ld4(mu + (size_t)b * NDIM + 8 * tid);
    float4 m1 = ld4(mu + (size_t)b * NDIM + 8 * tid + 4);
    mu8[0] = m0.x; mu8[1] = m0.y; mu8[2] = m0.z; mu8[3] = m0.w;
    mu8[4] = m1.x; mu8[5] = m1.y; mu8[6] = m1.z; mu8[7] = m1.w;
  }
  __syncthreads();
  float t = 1.0f;
  for (int it = 0; it < N_ITERS; it++) {
    matvec_partial(Sb, yv, zsc, g, c);
    __syncthreads();
    if (tid < 64) {
      float z8[8], v8[8]; combine_z(zsc, tid, z8);
#pragma unroll
      for (int k = 0; k < 8; k++) v8[k] = y8[k] - step * (2.0f * z8[k] - mu8[k]);
      float th = -1e30f;
      for (int m = 0; m < 64; m++) {
        float s = 0.f, cn = 0.f;
#pragma unroll
        for (int k = 0; k < 8; k++) if (v8[k] > th) { s += v8[k]; cn += 1.f; }
#pragma unroll
        for (int off = 1; off < 64; off <<= 1) { s += __shfl_xor(s, off, 64); cn += __shfl_xor(cn, off, 64); }
        float thn = (s - 1.0f) / cn;
        if (!(thn > th)) break;
        th = thn;
      }
      float tn = 0.5f * (1.0f + sqrtf(1.0f + 4.0f * t * t));
      float coef = (t - 1.0f) / tn;
#pragma unroll
      for (int k = 0; k < 8; k++) {
        float wn = fmaxf(v8[k] - th, 0.0f);
        y8[k] = wn + coef * (wn - w8[k]);
        w8[k] = wn;
      }
      *(float4*)(yv + 8 * tid)     = make_float4(y8[0], y8[1], y8[2], y8[3]);
      *(float4*)(yv + 8 * tid + 4) = make_float4(y8[4], y8[5], y8[6], y8[7]);
      t = tn;
    }
    __syncthreads();
  }
  if (tid < 64) {
    *(float4*)(out + (size_t)b * NDIM + 8 * tid)     = make_float4(w8[0], w8[1], w8[2], w8[3]);
    *(float4*)(out + (size_t)b * NDIM + 8 * tid + 4) = make_float4(w8[4], w8[5], w8[6], w8[7]);
  }
}

// ---------------- launch ----------------
extern "C" void kernel_launch(void* const* d_in, const int* in_sizes, int n_in,
                              void* d_out, int out_size, void* d_ws, size_t ws_size,
                              hipStream_t stream) {
  const float* mu = (const float*)d_in[0];
  float* Sg = (float*)d_in[1];
  if (n_in >= 2 && in_sizes[0] > in_sizes[1]) { mu = (const float*)d_in[1]; Sg = (float*)d_in[0]; }
  float* out = (float*)d_out;

  const size_t need = (size_t)BATCH * NPAIR * NDIM * sizeof(half2_t);  // 64 MB
  if (ws_size >= need) {
    half2_t* Sh = (half2_t*)d_ws;
    sym_conv_kernel<<<dim3(BATCH, 16, 16), dim3(32, 8), 0, stream>>>(Sg, Sh);
    qp_solver_h<<<dim3(BATCH), dim3(512), 0, stream>>>(mu, Sh, out);
  } else {
    symmetrize_kernel<<<dim3(BATCH, 16, 16), dim3(32, 8), 0, stream>>>(Sg);
    qp_solver<<<dim3(BATCH), dim3(512), 0, stream>>>(mu, Sg, out);
  }
}